// Round 1
// baseline (94.494 us; speedup 1.0000x reference)
//
#include <hip/hip_runtime.h>

#define HOP       256
#define FRAMELEN  512
#define FLEN      64
#define WD        32
#define NSTEP     416          // (FRAMELEN - FLEN) - WD
#define NFRM      4096
#define TLEN      1048832      // FRAMELEN + HOP*(NFRM-1)
#define LROW      786688       // 448 + 4095*192
#define WCLIP     65535.0f

// DPP-based add: v += dpp_permuted(v), invalid lanes contribute 0.
template<int CTRL>
__device__ __forceinline__ float dpp_add(float v) {
    int t = __builtin_amdgcn_update_dpp(0, __float_as_int(v), CTRL, 0xF, 0xF, true);
    return v + __int_as_float(t);
}

// Full wave64 sum, result broadcast as a scalar (SGPR) via readlane(63).
__device__ __forceinline__ float wave_sum63(float v) {
    v = dpp_add<0x111>(v);   // row_shr:1
    v = dpp_add<0x112>(v);   // row_shr:2
    v = dpp_add<0x114>(v);   // row_shr:4
    v = dpp_add<0x118>(v);   // row_shr:8  -> lane15 of each row = row sum
    v = dpp_add<0x142>(v);   // row_bcast:15 -> lane31 = sum(0..31), lane63 = sum(32..63 rows 2+3 partial)
    v = dpp_add<0x143>(v);   // row_bcast:31 -> lane63 = total
    return __int_as_float(__builtin_amdgcn_readlane(__float_as_int(v), 63));
}

// One LMS step. Reference fp32 op order: prod = (MU*e)*xi; w = clip(w + prod).
#define LMS_STEP(T, STORE) do {                                   \
    float xi = lxf[(T) + lane];                                   \
    float p  = w * xi;                                            \
    float s  = wave_sum63(p);        /* d_est */                  \
    float dv = ldf[(T)];                                          \
    float e  = dv - s;                                            \
    if ((STORE) && lane == 0) { od[(T)] = s; oe[(T)] = e; }       \
    float pr = (0.05f * e) * xi;                                  \
    float wn = w + pr;                                            \
    w = fminf(fmaxf(wn, -WCLIP), WCLIP);                          \
} while (0)

__global__ void __launch_bounds__(256, 8)
lms_kernel(const float* __restrict__ dmat, const float* __restrict__ xvec,
           float* __restrict__ out)
{
    __shared__ float lx[768];        // x[f0*HOP .. +768)
    __shared__ float ld[2][672];     // d[b][f0*HOP+WD .. +672)

    const int tid  = threadIdx.x;
    const int lane = tid & 63;
    const int wv   = tid >> 6;       // 0..3
    const int f0   = blockIdx.x * 2;
    const int xg   = f0 * HOP;

    #pragma unroll
    for (int i = 0; i < 3; ++i)
        lx[tid + 256 * i] = xvec[xg + tid + 256 * i];

    for (int i = tid; i < 1344; i += 256) {
        int bb = (i >= 672) ? 1 : 0;
        int j  = i - bb * 672;
        ld[bb][j] = dmat[(size_t)bb * TLEN + xg + WD + j];
    }
    __syncthreads();

    const int df = wv >> 1;          // which of the 2 frames in this block
    const int b  = wv & 1;           // batch row
    const int f  = f0 + df;

    const float* lxf = lx + df * HOP;
    const float* ldf = ld[b] + df * HOP;

    // output row position: 32 + 192*f + t
    float* od = out + (size_t)b * LROW + 32 + (size_t)192 * f;
    float* oe = od + (size_t)2 * LROW;

    if (f == 0 && lane < WD) {       // leading zeros of each row
        out[(size_t)b * LROW + lane] = 0.0f;
        out[(size_t)2 * LROW + (size_t)b * LROW + lane] = 0.0f;
    }

    float w = 0.0f;

    if (f == 0) {
        #pragma unroll 8
        for (int t = 0; t < NSTEP; ++t) LMS_STEP(t, true);
    } else {
        #pragma unroll 8
        for (int t = 0; t < 224; ++t)  LMS_STEP(t, false);
        #pragma unroll 8
        for (int t = 224; t < NSTEP; ++t) LMS_STEP(t, true);
    }
}

extern "C" void kernel_launch(void* const* d_in, const int* in_sizes, int n_in,
                              void* d_out, int out_size, void* d_ws, size_t ws_size,
                              hipStream_t stream) {
    const float* dmat = (const float*)d_in[0];   // (2, TLEN)
    const float* xvec = (const float*)d_in[1];   // (TLEN,)
    float* out = (float*)d_out;                  // [d_est(2,LROW), e(2,LROW)] flat

    hipLaunchKernelGGL(lms_kernel, dim3(NFRM / 2), dim3(256), 0, stream,
                       dmat, xvec, out);
}

// Round 2
// 46.026 us; speedup vs baseline: 2.0531x; 2.0531x over previous
//
#include <hip/hip_runtime.h>

#define HOP       256
#define WD        32
#define NSTEP     416          // (FRAMELEN - FILTERLEN) - WD
#define NFRM      4096
#define TLEN      1048832      // FRAMELEN + HOP*(NFRM-1)
#define LROW      786688       // 448 + 4095*192
#define FPB       8            // frames per block
#define XW        2272         // 7*HOP + 480 x-floats staged per block
#define DW        2208         // d-floats per batch per block
#define DWP       2244         // padded (stride % 32 == 4 -> bank spread)

// 16-lane butterfly sum within each row of 16 lanes; result in ALL lanes.
// quad_perm[1,0,3,2]=0xB1, quad_perm[2,3,0,1]=0x4E, row_half_mirror=0x141,
// row_mirror=0x140. All lanes valid -> masks full.
__device__ __forceinline__ float row_sum16(float v) {
    v += __int_as_float(__builtin_amdgcn_update_dpp(0, __float_as_int(v), 0xB1,  0xF, 0xF, true));
    v += __int_as_float(__builtin_amdgcn_update_dpp(0, __float_as_int(v), 0x4E,  0xF, 0xF, true));
    v += __int_as_float(__builtin_amdgcn_update_dpp(0, __float_as_int(v), 0x141, 0xF, 0xF, true));
    v += __int_as_float(__builtin_amdgcn_update_dpp(0, __float_as_int(v), 0x140, 0xF, 0xF, true));
    return v;
}

__device__ __forceinline__ float clampw(float v) {
    return fminf(fmaxf(v, -65535.0f), 65535.0f);
}

// One wave = 4 chains (rows of 16 lanes), 4 taps per lane.
// Block = 4 waves = 16 chains = 8 frames x 2 batches. Grid = 512 blocks.
__global__ void __launch_bounds__(256, 2)
lms_kernel(const float* __restrict__ dmat, const float* __restrict__ xvec,
           float* __restrict__ out)
{
    __shared__ float lx[XW];
    __shared__ float ld[2][DWP];

    const int tid   = threadIdx.x;
    const int f_blk = blockIdx.x * FPB;
    const size_t xg = (size_t)f_blk * HOP;

    // ---- stage x (2272 floats) and d (2 x 2208 floats) via float4 ----
    {
        const float4* __restrict__ sx = (const float4*)(xvec + xg);
        float4* dx = (float4*)lx;
        #pragma unroll
        for (int i = 0; i < 3; ++i) {
            int k = tid + 256 * i;
            if (k < XW / 4) dx[k] = sx[k];
        }
        const float4* __restrict__ s0 = (const float4*)(dmat + xg + WD);
        const float4* __restrict__ s1 = (const float4*)(dmat + (size_t)TLEN + xg + WD);
        float4* d0 = (float4*)ld[0];
        float4* d1 = (float4*)ld[1];
        #pragma unroll
        for (int i = 0; i < 3; ++i) {
            int k = tid + 256 * i;
            if (k < DW / 4) { d0[k] = s0[k]; d1[k] = s1[k]; }
        }
    }
    __syncthreads();

    const int lane = tid & 63;
    const int wv   = tid >> 6;
    const int row  = lane >> 4;        // 0..3 within wave
    const int col  = lane & 15;        // tap group: taps 4c..4c+3
    const int fl   = 2 * wv + (row >> 1);   // local frame 0..7
    const int b    = row & 1;               // batch
    const int f    = f_blk + fl;            // global frame

    const float* __restrict__ lxp = lx + fl * HOP + 4 * col; // xi[j] = lxp[t+j]
    const float* __restrict__ ldp = ld[b] + fl * HOP;        // dv    = ldp[t]

    float* od = out + (size_t)b * LROW + 32 + (size_t)192 * f;
    float* oe = od + 2 * (size_t)LROW;

    // leading 32 zeros of each of the 4 output rows (d_est b0,b1, e b0,b1)
    if (f_blk == 0 && tid < 128) {
        out[(size_t)(tid >> 5) * LROW + (tid & 31)] = 0.0f;
    }

    float w0 = 0.f, w1 = 0.f, w2 = 0.f, w3 = 0.f;
    const bool st1 = (col == 0) && (f == 0);  // phase-1 writers (frame 0 only)
    const bool st2 = (col == 0);              // phase-2 writers (all frames)

    #pragma unroll 8
    for (int t = 0; t < 224; ++t) {
        float x0 = lxp[t], x1 = lxp[t + 1], x2 = lxp[t + 2], x3 = lxp[t + 3];
        float p = w0 * x0 + w1 * x1 + w2 * x2 + w3 * x3;
        float s = row_sum16(p);                 // d_est, in all 16 row lanes
        float e = ldp[t] - s;
        if (st1) { od[t] = s; oe[t] = e; }
        float g = 0.05f * e;
        w0 = clampw(fmaf(g, x0, w0));
        w1 = clampw(fmaf(g, x1, w1));
        w2 = clampw(fmaf(g, x2, w2));
        w3 = clampw(fmaf(g, x3, w3));
    }
    #pragma unroll 8
    for (int t = 224; t < NSTEP; ++t) {
        float x0 = lxp[t], x1 = lxp[t + 1], x2 = lxp[t + 2], x3 = lxp[t + 3];
        float p = w0 * x0 + w1 * x1 + w2 * x2 + w3 * x3;
        float s = row_sum16(p);
        float e = ldp[t] - s;
        if (st2) { od[t] = s; oe[t] = e; }
        float g = 0.05f * e;
        w0 = clampw(fmaf(g, x0, w0));
        w1 = clampw(fmaf(g, x1, w1));
        w2 = clampw(fmaf(g, x2, w2));
        w3 = clampw(fmaf(g, x3, w3));
    }
}

extern "C" void kernel_launch(void* const* d_in, const int* in_sizes, int n_in,
                              void* d_out, int out_size, void* d_ws, size_t ws_size,
                              hipStream_t stream) {
    const float* dmat = (const float*)d_in[0];   // (2, TLEN)
    const float* xvec = (const float*)d_in[1];   // (TLEN,)
    float* out = (float*)d_out;                  // [d_est(2,LROW), e(2,LROW)]

    hipLaunchKernelGGL(lms_kernel, dim3(NFRM / FPB), dim3(256), 0, stream,
                       dmat, xvec, out);
}